// Round 1
// baseline (796.128 us; speedup 1.0000x reference)
//
#include <hip/hip_runtime.h>
#include <hip/hip_bf16.h>
#include <stdint.h>

// StaticQuantLinear: y = (clip(round(x/act_scale)) @ unpack_int4(W)^T) * (act_scale*wscale) + bias
// M=32, IN=8192, OUT=32768. Weight stream = 512 MiB int32 -> memory-bound.
#define M_DIM  32
#define IN_FEAT 8192
#define OUT_FEAT 32768
#define KSPLIT 4
#define KSLICE (IN_FEAT / KSPLIT)   // 2048

typedef __attribute__((ext_vector_type(8))) __bf16 bf16x8;
typedef __attribute__((ext_vector_type(4))) float f32x4;
typedef __attribute__((ext_vector_type(4))) int   i32x4;
typedef __attribute__((ext_vector_type(8))) unsigned short u16x8;

// Quantize x -> bf16 integers in [-127,127]; exact (ints <= 127 fit bf16 mantissa).
__global__ void quant_kernel(const float* __restrict__ x,
                             const float* __restrict__ act_scale,
                             unsigned short* __restrict__ xq) {
  int i = blockIdx.x * blockDim.x + threadIdx.x;
  float s = act_scale[0];
  float q = rintf(x[i] / s);                 // RNE, matches jnp.round semantics
  q = fminf(fmaxf(q, -127.0f), 127.0f);
  unsigned int u = __builtin_bit_cast(unsigned int, q);
  xq[i] = (unsigned short)(u >> 16);         // truncation exact: low mantissa bits are 0
}

// One wave: 16 output cols x all 32 rows, over a K-slice of 2048.
// mfma_f32_16x16x32_bf16: A[m=lane&15][k=(lane>>4)*8+j], B[k][n] same pattern
// on the B^T ([N][K]) weight layout; C/D: col=lane&15, row=(lane>>4)*4+reg.
__global__ __launch_bounds__(256) void gemm_kernel(
    const unsigned short* __restrict__ xq,   // [32][8192] bf16 bits
    const int*   __restrict__ wp,            // [32768][4096] int32 (one byte = 2 nibbles)
    const float* __restrict__ wscale,        // [32768]
    const float* __restrict__ act_scale,     // [1]
    const float* __restrict__ bias,          // [32768]
    float* __restrict__ out)                 // [32][32768], pre-zeroed
{
  const int lane  = threadIdx.x & 63;
  const int wave  = threadIdx.x >> 6;        // 0..3
  const int l15   = lane & 15;
  const int krow  = lane >> 4;               // 0..3

  const int kslice = blockIdx.x & (KSPLIT - 1);
  const int nblk   = blockIdx.x >> 2;        // 0..511
  const int n      = (nblk << 6) + (wave << 4) + l15;

  const int kbase = kslice * KSLICE;
  const int k0    = kbase + krow * 8;

  const u16x8* a0p = (const u16x8*)(xq + (size_t)l15        * IN_FEAT);
  const u16x8* a1p = (const u16x8*)(xq + (size_t)(l15 + 16) * IN_FEAT);
  const i32x4* bp  = (const i32x4*)(wp + (size_t)n * (IN_FEAT / 2));

  f32x4 acc0 = {0.f, 0.f, 0.f, 0.f};
  f32x4 acc1 = {0.f, 0.f, 0.f, 0.f};

#pragma unroll 4
  for (int k = k0; k < kbase + KSLICE; k += 32) {
    // A fragments: 16 B each, L2-resident (x_q is only 512 KB)
    u16x8 a0u = a0p[k >> 3];
    u16x8 a1u = a1p[k >> 3];
    // B: 4 packed int32 = 8 consecutive int4 weights along K (streaming, nontemporal)
    i32x4 w4 = __builtin_nontemporal_load(&bp[k >> 3]);

    union { unsigned int u[4]; bf16x8 v; } bu;
#pragma unroll
    for (int j = 0; j < 4; ++j) {
      int v  = w4[j];
      int lo = ((v & 15) ^ 8) - 8;           // sign-extend nibble (k even)
      int hi = (((v >> 4) & 15) ^ 8) - 8;    // (k odd)
      unsigned int ulo = __builtin_bit_cast(unsigned int, (float)lo);
      unsigned int uhi = __builtin_bit_cast(unsigned int, (float)hi);
      bu.u[j] = (ulo >> 16) | (uhi & 0xFFFF0000u);  // bf16 pair, exact
    }

    bf16x8 a0 = __builtin_bit_cast(bf16x8, a0u);
    bf16x8 a1 = __builtin_bit_cast(bf16x8, a1u);
    acc0 = __builtin_amdgcn_mfma_f32_16x16x32_bf16(a0, bu.v, acc0, 0, 0, 0);
    acc1 = __builtin_amdgcn_mfma_f32_16x16x32_bf16(a1, bu.v, acc1, 0, 0, 0);
  }

  const float sc = act_scale[0] * wscale[n];
  const float bs = bias[n];
  const int m0 = krow * 4;
#pragma unroll
  for (int r = 0; r < 4; ++r) {
    float v0 = acc0[r] * sc;
    float v1 = acc1[r] * sc;
    if (kslice == 0) { v0 += bs; v1 += bs; } // bias added exactly once per (m,n)
    atomicAdd(out + (size_t)(m0 + r)      * OUT_FEAT + n, v0);
    atomicAdd(out + (size_t)(m0 + r + 16) * OUT_FEAT + n, v1);
  }
}

extern "C" void kernel_launch(void* const* d_in, const int* in_sizes, int n_in,
                              void* d_out, int out_size, void* d_ws, size_t ws_size,
                              hipStream_t stream) {
  const float* x      = (const float*)d_in[0];
  const int*   wp     = (const int*)  d_in[1];
  const float* wscale = (const float*)d_in[2];
  const float* ascale = (const float*)d_in[3];
  const float* bias   = (const float*)d_in[4];
  float* out = (float*)d_out;
  unsigned short* xq = (unsigned short*)d_ws;   // 32*8192*2 = 512 KB scratch

  // d_out is re-poisoned before every launch; atomics need zeros.
  hipMemsetAsync(out, 0, (size_t)M_DIM * OUT_FEAT * sizeof(float), stream);
  quant_kernel<<<(M_DIM * IN_FEAT) / 256, 256, 0, stream>>>(x, ascale, xq);
  gemm_kernel<<<(OUT_FEAT / 64) * KSPLIT, 256, 0, stream>>>(xq, wp, wscale, ascale, bias, out);
}

// Round 3
// 730.165 us; speedup vs baseline: 1.0903x; 1.0903x over previous
//
#include <hip/hip_runtime.h>
#include <stdint.h>

// StaticQuantLinear: y = (clip(round(x/act_scale)) @ unpack_int4(W)^T) * (act_scale*wscale) + bias
// M=32, IN=8192, OUT=32768. weight_packed: [32768][4096] int32, LOW BYTE ONLY
// (2 int4 nibbles per int32). 512 MiB weight stream -> memory-bound, roofline ~83 us.
//
// Strategy: int8 MFMA (mfma_i32_16x16x64_i8), weights unpacked to (w<<4) int8
// via shift/or/and/perm (no float cvt), x quantized to int8. Exact int32
// accumulation into K-split partials in d_ws, then fused reduce+scale+bias.
//
// R2 post-mortem: (v*0x110)&0xF0F0 had a carry bug — (L+H)*256 overflows into
// bit 12 when L+H>=16, corrupting the upper weight by +1 (~47% of odd-k
// weights). Fixed with ((v<<4)|(v<<8))&0xF0F0, which has no cross terms.

#define M_DIM  32
#define IN_FEAT 8192
#define OUT_FEAT 32768
#define KSPLIT 4
#define KSLICE (IN_FEAT / KSPLIT)   // 2048
#define NITER  (KSLICE / 64)        // 32 iterations of K=64 per wave

typedef __attribute__((ext_vector_type(4))) int   i32x4;
typedef __attribute__((ext_vector_type(4))) float f32x4;

// ---- quantize x -> int8, packed 4/thread ----------------------------------
__global__ __launch_bounds__(256) void quant_kernel(
    const float* __restrict__ x,
    const float* __restrict__ act_scale,
    int* __restrict__ xq4) {            // [M*IN/4] packed int8x4
  int i = blockIdx.x * blockDim.x + threadIdx.x;
  float s = act_scale[0];
  f32x4 v = ((const f32x4*)x)[i];
  int r = 0;
#pragma unroll
  for (int j = 0; j < 4; ++j) {
    float q = rintf(v[j] / s);                       // RNE, matches jnp.round
    q = fminf(fmaxf(q, -127.0f), 127.0f);
    r |= ((int)q & 0xFF) << (8 * j);
  }
  xq4[i] = r;
}

// unpack one packed int32's low byte (2 nibbles) -> bytes [L<<4, H<<4] in
// bits 0-15. No carry hazards: bits 4-7 come only from v<<4, bits 12-15
// only from v<<8.
__device__ __forceinline__ int unpack2(int v) {
  return ((v << 4) | (v << 8)) & 0xF0F0;
}

// ---- int8 GEMM into int32 partials ----------------------------------------
// Wave: 16 output cols (n) x 32 rows (m), K-slice of 2048.
// Per iter: K=64. Lane(l15,krow): A bytes k = kc + krow*16 .. +16 (16B x2 for
// the two m halves), B = same k range = 8 packed int32 (32B). A and B use the
// same (krow, byte)->k map, so the contraction pairs correctly.
__global__ __launch_bounds__(256) void gemm_kernel(
    const char* __restrict__ xq,        // [32][8192] int8
    const int*  __restrict__ wp,        // [32768][4096] int32 (low byte = 2 nibbles)
    int* __restrict__ partial)          // [KSPLIT][32][32768] int32
{
  const int lane = threadIdx.x & 63;
  const int wave = threadIdx.x >> 6;    // 0..3
  const int l15  = lane & 15;
  const int krow = lane >> 4;           // 0..3

  const int kslice = blockIdx.x & (KSPLIT - 1);
  const int nblk   = blockIdx.x >> 2;   // 0..511
  const int n      = (nblk << 6) + (wave << 4) + l15;
  const int kbase  = kslice * KSLICE;

  // A rows (int8, row-major): i32x4 index i*4 + krow covers k = kbase + i*64 + krow*16 .. +16
  const i32x4* a0p = (const i32x4*)(xq + (size_t)l15        * IN_FEAT + kbase);
  const i32x4* a1p = (const i32x4*)(xq + (size_t)(l15 + 16) * IN_FEAT + kbase);
  // B row n: weight k lives in int32 index k>>1 (byte offset 2k).
  // i32x4 index i*8 + krow*2 (+1) covers k = kbase + i*64 + krow*16 .. +16
  const i32x4* bp  = (const i32x4*)((const char*)(wp + (size_t)n * (IN_FEAT / 2))
                                    + (size_t)kbase * 2);

  i32x4 acc0 = {0, 0, 0, 0};
  i32x4 acc1 = {0, 0, 0, 0};

  // prefetch iter 0
  i32x4 w_lo = __builtin_nontemporal_load(&bp[krow * 2]);
  i32x4 w_hi = __builtin_nontemporal_load(&bp[krow * 2 + 1]);
  i32x4 a0   = a0p[krow];
  i32x4 a1   = a1p[krow];

#pragma unroll 2
  for (int i = 0; i < NITER; ++i) {
    const int ip = (i + 1 < NITER) ? (i + 1) : (NITER - 1);  // clamped prefetch (in-bounds)
    i32x4 w_lo_n = __builtin_nontemporal_load(&bp[ip * 8 + krow * 2]);
    i32x4 w_hi_n = __builtin_nontemporal_load(&bp[ip * 8 + krow * 2 + 1]);
    i32x4 a0_n   = a0p[ip * 4 + krow];
    i32x4 a1_n   = a1p[ip * 4 + krow];

    // unpack 8 int32 -> 16 int8 of (w<<4); perm pool = {src1 bytes 0-3, src0 bytes 4-7}
    int p0 = unpack2(w_lo[0]);
    int p1 = unpack2(w_lo[1]);
    int p2 = unpack2(w_lo[2]);
    int p3 = unpack2(w_lo[3]);
    int p4 = unpack2(w_hi[0]);
    int p5 = unpack2(w_hi[1]);
    int p6 = unpack2(w_hi[2]);
    int p7 = unpack2(w_hi[3]);
    i32x4 bfrag;
    bfrag[0] = __builtin_amdgcn_perm(p1, p0, 0x05040100);  // bytes [w0,w1,w2,w3] <<4
    bfrag[1] = __builtin_amdgcn_perm(p3, p2, 0x05040100);  // w4..w7
    bfrag[2] = __builtin_amdgcn_perm(p5, p4, 0x05040100);  // w8..w11
    bfrag[3] = __builtin_amdgcn_perm(p7, p6, 0x05040100);  // w12..w15

    acc0 = __builtin_amdgcn_mfma_i32_16x16x64_i8(a0, bfrag, acc0, 0, 0, 0);
    acc1 = __builtin_amdgcn_mfma_i32_16x16x64_i8(a1, bfrag, acc1, 0, 0, 0);

    w_lo = w_lo_n; w_hi = w_hi_n; a0 = a0_n; a1 = a1_n;
  }

  // C/D layout (shape-determined): col = lane&15, row = krow*4 + reg
  int* pout = partial + (size_t)kslice * (M_DIM * OUT_FEAT);
  const int m0 = krow * 4;
#pragma unroll
  for (int r = 0; r < 4; ++r) {
    __builtin_nontemporal_store(acc0[r], &pout[(size_t)(m0 + r)      * OUT_FEAT + n]);
    __builtin_nontemporal_store(acc1[r], &pout[(size_t)(m0 + r + 16) * OUT_FEAT + n]);
  }
}

// ---- reduce K-splits, scale (incl. 1/16 for the w<<4 trick), add bias -----
__global__ __launch_bounds__(256) void reduce_kernel(
    const int*   __restrict__ partial,  // [KSPLIT][32][32768]
    const float* __restrict__ wscale,   // [32768]
    const float* __restrict__ act_scale,
    const float* __restrict__ bias,     // [32768]
    float* __restrict__ out)            // [32][32768]
{
  const int t  = blockIdx.x * blockDim.x + threadIdx.x;   // 0 .. 262143
  const int m  = t >> 13;               // /(OUT_FEAT/4)
  const int n4 = (t & 8191) << 2;
  const size_t off = (size_t)m * OUT_FEAT + n4;

  i32x4 s = *(const i32x4*)(partial + off);
#pragma unroll
  for (int k = 1; k < KSPLIT; ++k)
    s += *(const i32x4*)(partial + (size_t)k * (M_DIM * OUT_FEAT) + off);

  const float as = act_scale[0] * (1.0f / 16.0f);         // undo w<<4
  f32x4 ws = *(const f32x4*)(wscale + n4);
  f32x4 bs = *(const f32x4*)(bias + n4);
  f32x4 r;
#pragma unroll
  for (int j = 0; j < 4; ++j)
    r[j] = (float)s[j] * (as * ws[j]) + bs[j];
  *(f32x4*)(out + off) = r;
}

extern "C" void kernel_launch(void* const* d_in, const int* in_sizes, int n_in,
                              void* d_out, int out_size, void* d_ws, size_t ws_size,
                              hipStream_t stream) {
  const float* x      = (const float*)d_in[0];
  const int*   wp     = (const int*)  d_in[1];
  const float* wscale = (const float*)d_in[2];
  const float* ascale = (const float*)d_in[3];
  const float* bias   = (const float*)d_in[4];
  float* out = (float*)d_out;

  int*  partial = (int*)d_ws;                               // 16 MiB
  char* xq      = (char*)d_ws + (size_t)KSPLIT * M_DIM * OUT_FEAT * sizeof(int);  // 256 KiB

  quant_kernel<<<(M_DIM * IN_FEAT / 4) / 256, 256, 0, stream>>>(x, ascale, (int*)xq);
  gemm_kernel<<<(OUT_FEAT / 64) * KSPLIT, 256, 0, stream>>>(xq, wp, partial);
  reduce_kernel<<<(M_DIM * OUT_FEAT / 4) / 256, 256, 0, stream>>>(partial, wscale, ascale, bias, out);
}

// Round 4
// 713.942 us; speedup vs baseline: 1.1151x; 1.0227x over previous
//
#include <hip/hip_runtime.h>
#include <stdint.h>

// StaticQuantLinear: y = (clip(round(x/act_scale)) @ unpack_int4(W)^T) * (act_scale*wscale) + bias
// M=32, IN=8192, OUT=32768. weight_packed: [32768][4096] int32, low byte = 2 nibbles.
// 512 MiB weight stream -> memory-bound, gemm roofline ~83 us.
//
// R4: full-64B-line-per-instruction B loads (w_lo = bp[i*8+krow] covers one
// contiguous 64B line per row per instruction; R3's krow*32 pattern left every
// line half-covered per nt-instruction -> suspected 2x HBM over-fetch).
// xq is stored PERMUTED within each 64-k block so the A fragment matches the
// new B lane->k map byte-for-byte. Unpack cheapened via lshl_or byte-pack.

#define M_DIM  32
#define IN_FEAT 8192
#define OUT_FEAT 32768
#define KSPLIT 4
#define KSLICE (IN_FEAT / KSPLIT)   // 2048
#define NITER  (KSLICE / 64)        // 32 iterations of K=64 per wave

typedef __attribute__((ext_vector_type(4))) int   i32x4;
typedef __attribute__((ext_vector_type(4))) float f32x4;

// ---- quantize x -> int8, permuted layout ----------------------------------
// Within each 64-k block of a row, 8-k group g lands at byte offset:
//   g<4 ? g*16 : (g-4)*16+8
// so that lane krow's single 16B load at offset krow*16 holds k =
// {base+krow*8..+8} ++ {base+32+krow*8..+8}, matching the B-frag k order.
__global__ __launch_bounds__(256) void quant_kernel(
    const float* __restrict__ x,
    const float* __restrict__ act_scale,
    char* __restrict__ xq) {            // [32][8192] int8, permuted per 64-block
  const int t  = blockIdx.x * blockDim.x + threadIdx.x;   // 0..32767, 8 k each
  const int m  = t >> 10;              // IN/8 = 1024 groups per row
  const int g8 = t & 1023;
  const int k0 = g8 << 3;
  const int blk = k0 >> 6;
  const int g   = (k0 >> 3) & 7;
  const int pos = blk * 64 + ((g < 4) ? g * 16 : (g - 4) * 16 + 8);

  const float s = act_scale[0];
  const f32x4 v0 = *(const f32x4*)(x + (size_t)m * IN_FEAT + k0);
  const f32x4 v1 = *(const f32x4*)(x + (size_t)m * IN_FEAT + k0 + 4);
  int r0 = 0, r1 = 0;
#pragma unroll
  for (int j = 0; j < 4; ++j) {
    float qa = fminf(fmaxf(rintf(v0[j] / s), -127.0f), 127.0f);  // RNE == jnp.round
    float qb = fminf(fmaxf(rintf(v1[j] / s), -127.0f), 127.0f);
    r0 |= ((int)qa & 0xFF) << (8 * j);
    r1 |= ((int)qb & 0xFF) << (8 * j);
  }
  int* dst = (int*)(xq + (size_t)m * IN_FEAT + pos);   // 8-byte aligned
  dst[0] = r0;
  dst[1] = r1;
}

// ---- int8 GEMM into int32 partials ----------------------------------------
// Wave: 16 output cols (n) x 32 rows (m), K-slice of 2048, K=64 per iter.
// B: lane(l15,krow) loads bp[i*8+krow] (k = 64i+8krow..+8) and bp[i*8+4+krow]
// (k = 64i+32+8krow..+8). Per instruction, each row's 4 krow lanes cover one
// contiguous 64B line. A (permuted xq) provides identical k order.
__global__ __launch_bounds__(256) void gemm_kernel(
    const char* __restrict__ xq,        // [32][8192] int8 (permuted blocks)
    const int*  __restrict__ wp,        // [32768][4096] int32 (low byte = 2 nibbles)
    int* __restrict__ partial)          // [KSPLIT][32][32768] int32
{
  const int lane = threadIdx.x & 63;
  const int wave = threadIdx.x >> 6;    // 0..3
  const int l15  = lane & 15;
  const int krow = lane >> 4;           // 0..3

  const int kslice = blockIdx.x & (KSPLIT - 1);
  const int nblk   = blockIdx.x >> 2;   // 0..511
  const int n      = (nblk << 6) + (wave << 4) + l15;
  const int kbase  = kslice * KSLICE;

  const i32x4* a0p = (const i32x4*)(xq + (size_t)l15        * IN_FEAT + kbase);
  const i32x4* a1p = (const i32x4*)(xq + (size_t)(l15 + 16) * IN_FEAT + kbase);
  const i32x4* bp  = (const i32x4*)((const char*)(wp + (size_t)n * (IN_FEAT / 2))
                                    + (size_t)kbase * 2);

  i32x4 acc0 = {0, 0, 0, 0};
  i32x4 acc1 = {0, 0, 0, 0};

  // prefetch iter 0
  i32x4 w_lo = __builtin_nontemporal_load(&bp[krow]);
  i32x4 w_hi = __builtin_nontemporal_load(&bp[4 + krow]);
  i32x4 a0   = a0p[krow];
  i32x4 a1   = a1p[krow];

#pragma unroll 2
  for (int i = 0; i < NITER; ++i) {
    const int ip = (i + 1 < NITER) ? (i + 1) : (NITER - 1);  // clamped (in-bounds)
    i32x4 w_lo_n = __builtin_nontemporal_load(&bp[ip * 8 + krow]);
    i32x4 w_hi_n = __builtin_nontemporal_load(&bp[ip * 8 + 4 + krow]);
    i32x4 a0_n   = a0p[ip * 4 + krow];
    i32x4 a1_n   = a1p[ip * 4 + krow];

    // pack 4 zero-extended low bytes -> 1 reg, isolate nibbles (<<4), interleave.
    // byte j of b covers k pair (2j, 2j+1): low nibble = even k, high = odd k.
    int b0  = w_lo[0] | (w_lo[1] << 8) | (w_lo[2] << 16) | (w_lo[3] << 24);
    int b1  = w_hi[0] | (w_hi[1] << 8) | (w_hi[2] << 16) | (w_hi[3] << 24);
    int lo0 = (b0 << 4) & 0xF0F0F0F0;   // (w<<4) for even k
    int hi0 =  b0       & 0xF0F0F0F0;   // (w<<4) for odd k
    int lo1 = (b1 << 4) & 0xF0F0F0F0;
    int hi1 =  b1       & 0xF0F0F0F0;
    i32x4 bfrag;
    bfrag[0] = __builtin_amdgcn_perm(hi0, lo0, 0x05010400);  // [L0,H0,L1,H1]
    bfrag[1] = __builtin_amdgcn_perm(hi0, lo0, 0x07030602);  // [L2,H2,L3,H3]
    bfrag[2] = __builtin_amdgcn_perm(hi1, lo1, 0x05010400);
    bfrag[3] = __builtin_amdgcn_perm(hi1, lo1, 0x07030602);

    acc0 = __builtin_amdgcn_mfma_i32_16x16x64_i8(a0, bfrag, acc0, 0, 0, 0);
    acc1 = __builtin_amdgcn_mfma_i32_16x16x64_i8(a1, bfrag, acc1, 0, 0, 0);

    w_lo = w_lo_n; w_hi = w_hi_n; a0 = a0_n; a1 = a1_n;
  }

  // C/D layout (shape-determined): col = lane&15, row = krow*4 + reg
  int* pout = partial + (size_t)kslice * (M_DIM * OUT_FEAT);
  const int m0 = krow * 4;
#pragma unroll
  for (int r = 0; r < 4; ++r) {
    __builtin_nontemporal_store(acc0[r], &pout[(size_t)(m0 + r)      * OUT_FEAT + n]);
    __builtin_nontemporal_store(acc1[r], &pout[(size_t)(m0 + r + 16) * OUT_FEAT + n]);
  }
}

// ---- reduce K-splits, scale (incl. 1/16 for the w<<4 trick), add bias -----
__global__ __launch_bounds__(256) void reduce_kernel(
    const int*   __restrict__ partial,  // [KSPLIT][32][32768]
    const float* __restrict__ wscale,   // [32768]
    const float* __restrict__ act_scale,
    const float* __restrict__ bias,     // [32768]
    float* __restrict__ out)            // [32][32768]
{
  const int t  = blockIdx.x * blockDim.x + threadIdx.x;   // 0 .. 262143
  const int m  = t >> 13;
  const int n4 = (t & 8191) << 2;
  const size_t off = (size_t)m * OUT_FEAT + n4;

  i32x4 s = *(const i32x4*)(partial + off);
#pragma unroll
  for (int k = 1; k < KSPLIT; ++k)
    s += *(const i32x4*)(partial + (size_t)k * (M_DIM * OUT_FEAT) + off);

  const float as = act_scale[0] * (1.0f / 16.0f);         // undo w<<4
  f32x4 ws = *(const f32x4*)(wscale + n4);
  f32x4 bs = *(const f32x4*)(bias + n4);
  f32x4 r;
#pragma unroll
  for (int j = 0; j < 4; ++j)
    r[j] = (float)s[j] * (as * ws[j]) + bs[j];
  *(f32x4*)(out + off) = r;
}

extern "C" void kernel_launch(void* const* d_in, const int* in_sizes, int n_in,
                              void* d_out, int out_size, void* d_ws, size_t ws_size,
                              hipStream_t stream) {
  const float* x      = (const float*)d_in[0];
  const int*   wp     = (const int*)  d_in[1];
  const float* wscale = (const float*)d_in[2];
  const float* ascale = (const float*)d_in[3];
  const float* bias   = (const float*)d_in[4];
  float* out = (float*)d_out;

  int*  partial = (int*)d_ws;                               // 16 MiB
  char* xq      = (char*)d_ws + (size_t)KSPLIT * M_DIM * OUT_FEAT * sizeof(int);  // 256 KiB

  quant_kernel<<<(M_DIM * IN_FEAT / 8) / 256, 256, 0, stream>>>(x, ascale, xq);
  gemm_kernel<<<(OUT_FEAT / 64) * KSPLIT, 256, 0, stream>>>(xq, wp, partial);
  reduce_kernel<<<(M_DIM * OUT_FEAT / 4) / 256, 256, 0, stream>>>(partial, wscale, ascale, bias, out);
}